// Round 7
// baseline (588.156 us; speedup 1.0000x reference)
//
#include <hip/hip_runtime.h>

namespace {

typedef float v4f __attribute__((ext_vector_type(4)));

constexpr int   kB     = 32768;
constexpr int   kT     = 50;
constexpr float kDT    = 0.01f;
constexpr float kGamma = 0.1f;
constexpr float kSigma = 0.2f;
constexpr float kTau   = 0.5f;

// Packed-weight workspace layout (float offsets).
constexpr int WS_L1  = 0;              // [2 mlps][10 rows][20]  bias, w_t, w_x0..15, pad2
constexpr int WS_L2  = WS_L1  + 400;   // [2][10][12]            bias, w0..9, pad
constexpr int WS_L3  = WS_L2  + 240;   // [24][12]: rows 0..15 zW3, 16..23 pW3
constexpr int WS_UPD = WS_L3  + 288;   // [16][80]  Arow16 Brow8 Crow16 Drow8 Acol16 Ccol16
constexpr int WS_DH  = WS_UPD + 1280;  // [8][32]   Bcol16 Dcol16

__device__ __forceinline__ float ftanh(float x) {
  float e = exp2f(x * 2.8853900817779268f);   // exp(2x) via exp2
  return 1.0f - 2.0f * __builtin_amdgcn_rcpf(e + 1.0f);
}

// ---------------- prep: pack weights in per-wave consumption order ----------
__global__ __launch_bounds__(256) void prep_kernel(
    const float* __restrict__ A,   const float* __restrict__ Bm,
    const float* __restrict__ Cm,  const float* __restrict__ Dm,
    const float* __restrict__ pW1, const float* __restrict__ pb1,
    const float* __restrict__ pW2, const float* __restrict__ pb2,
    const float* __restrict__ pW3, const float* __restrict__ pb3,
    const float* __restrict__ zW1, const float* __restrict__ zb1,
    const float* __restrict__ zW2, const float* __restrict__ zb2,
    const float* __restrict__ zW3, const float* __restrict__ zb3,
    float* __restrict__ ws, float* __restrict__ out)
{
  const int tid = threadIdx.x;
  if (tid < 2) out[tid] = 0.0f;   // harness re-poisons out each replay
  // L1: m=0 -> z rows 0..9 ; m=1 -> phi rows 0..9
  for (int c = tid; c < 20; c += 256) {
    int m = c / 10, row = c % 10;
    const float* W = m ? pW1 : zW1;
    const float* b = m ? pb1 : zb1;
    float* d = ws + WS_L1 + c * 20;
    d[0] = b[row];
    for (int k = 0; k < 17; ++k) d[1 + k] = W[k * 10 + row];
    d[18] = 0.f; d[19] = 0.f;
  }
  // L2
  for (int c = tid; c < 20; c += 256) {
    int m = c / 10, row = c % 10;
    const float* W = m ? pW2 : zW2;
    const float* b = m ? pb2 : zb2;
    float* d = ws + WS_L2 + c * 12;
    d[0] = b[row];
    for (int k = 0; k < 10; ++k) d[1 + k] = W[k * 10 + row];
    d[11] = 0.f;
  }
  // L3: rows 0..15 = zW3 (wave0), rows 16..23 = pW3 rows 0..7 (wave1)
  for (int c = tid; c < 24; c += 256) {
    float* d = ws + WS_L3 + c * 12;
    if (c < 16) {
      d[0] = zb3[c];
      for (int k = 0; k < 10; ++k) d[1 + k] = zW3[k * 16 + c];
    } else {
      int row = c - 16;
      d[0] = pb3[row];
      for (int k = 0; k < 10; ++k) d[1 + k] = pW3[k * 8 + row];
    }
    d[11] = 0.f;
  }
  // UPD: per state row i: A row, B row, C row, D row, A col, C col
  for (int i = tid; i < 16; i += 256) {
    float* d = ws + WS_UPD + i * 80;
    for (int j = 0; j < 16; ++j) d[j]      = A [i * 16 + j];
    for (int j = 0; j < 8;  ++j) d[16 + j] = Bm[i * 8  + j];
    for (int j = 0; j < 16; ++j) d[24 + j] = Cm[i * 16 + j];
    for (int j = 0; j < 8;  ++j) d[40 + j] = Dm[i * 8  + j];
    for (int j = 0; j < 16; ++j) d[48 + j] = A [j * 16 + i];
    for (int j = 0; j < 16; ++j) d[64 + j] = Cm[j * 16 + i];
  }
  // DH: per control row i: B col, D col
  for (int i = tid; i < 8; i += 256) {
    float* d = ws + WS_DH + i * 32;
    for (int j = 0; j < 16; ++j) d[j]      = Bm[j * 8 + i];
    for (int j = 0; j < 16; ++j) d[16 + j] = Dm[j * 8 + i];
  }
}

// Wave-specialized UPD (8 rows, base 8Q) + dH (wave0: rows 0-1, wave1: 2-7).
template <int Q>
__device__ __forceinline__ void upd_dh(
    const float* __restrict__ Wup, const float* __restrict__ Wdh,
    const v4f x4[4], const v4f y4[4], const v4f zv4[4], const v4f u2[2],
    float dwv, v4f* __restrict__ Xn, v4f* __restrict__ Yn, float& s2)
{
#pragma unroll
  for (int r = 0; r < 8; ++r) {
    const float* w = Wup + r * 80;        // state row i = 8Q + r
    float dx = kGamma, fx = kSigma;
#pragma unroll
    for (int c = 0; c < 4; ++c)
#pragma unroll
      for (int j = 0; j < 4; ++j) {
        dx += w[4 * c + j]      * x4[c][j];
        fx += w[24 + 4 * c + j] * x4[c][j];
      }
#pragma unroll
    for (int c = 0; c < 2; ++c)
#pragma unroll
      for (int j = 0; j < 4; ++j) {
        dx += w[16 + 4 * c + j] * u2[c][j];
        fx += w[40 + 4 * c + j] * u2[c][j];
      }
    const float xi = x4[2 * Q + (r >> 2)][r & 3];
    const float yi = y4[2 * Q + (r >> 2)][r & 3];
    const float zi = zv4[2 * Q + (r >> 2)][r & 3];
    float dy = xi;
#pragma unroll
    for (int c = 0; c < 4; ++c)
#pragma unroll
      for (int j = 0; j < 4; ++j)
        dy += w[48 + 4 * c + j] * y4[c][j] + w[64 + 4 * c + j] * zv4[c][j];
    Xn[r >> 2][r & 3] = xi + kDT * dx + dwv * fx;
    Yn[r >> 2][r & 3] = yi - kDT * dy + dwv * zi;
  }
  constexpr int d0 = Q ? 2 : 0;
  constexpr int nd = Q ? 6 : 2;            // 2/6 split balances L3 16/8 rows
#pragma unroll
  for (int r = 0; r < nd; ++r) {
    const int i = d0 + r;
    const float* w = Wdh + i * 32;
    float dh = u2[i >> 2][i & 3];
#pragma unroll
    for (int c = 0; c < 4; ++c)
#pragma unroll
      for (int j = 0; j < 4; ++j)
        dh += w[4 * c + j] * y4[c][j] + w[16 + 4 * c + j] * zv4[c][j];
    s2 += dh * dh;
  }
}

// -------- main: 2 waves / 64 elements, zero redundancy, 2 barriers/step -----
// Wave0 = whole z-MLP; wave1 = whole phi-MLP; UPD rows 8/8; dH 2/6.
// waves_per_eu(2,2) caps occupancy -> 256-VGPR budget so the ~72-float live
// set stays in architectural VGPRs (R3-R5 were stuck at 60-64 VGPRs with
// AGPR-juggle VALU bloat ~2.2x the hand-counted stream).
__global__ __launch_bounds__(128)
__attribute__((amdgpu_waves_per_eu(2, 2)))
void bsde_kernel(
    const float* __restrict__ dw,  const float* __restrict__ X0,
    const float* __restrict__ yW1, const float* __restrict__ yb1,
    const float* __restrict__ yW2, const float* __restrict__ yb2,
    const float* __restrict__ yW3, const float* __restrict__ yb3,
    const float* __restrict__ ws,  float* __restrict__ out)
{
  __shared__ float XYt[64][36];   // dwords 0..15 = X, 16..31 = Y
  __shared__ float ZUt[64][28];   // 0..15 = Zv, 16..23 = u

  const int lane = threadIdx.x & 63;
  const int q    = __builtin_amdgcn_readfirstlane((int)(threadIdx.x >> 6));
  const int e    = blockIdx.x * 64 + lane;

  const float* Wl1 = ws + WS_L1  + q * 200;
  const float* Wl2 = ws + WS_L2  + q * 120;
  const float* Wl3 = ws + WS_L3  + q * 192;
  const float* Wup = ws + WS_UPD + q * 640;
  const float* Wdh = ws + WS_DH;

  // ---- X0 load (b128) + Y0 MLP (one-time, both waves full) ----
  v4f x4[4], y4[4];
#pragma unroll
  for (int c = 0; c < 4; ++c) x4[c] = *(const v4f*)&X0[e * 16 + 4 * c];

  {
    float h1t[10], h2t[10];
#pragma unroll
    for (int r = 0; r < 10; ++r) {
      float s = yb1[r];
#pragma unroll
      for (int c = 0; c < 4; ++c)
#pragma unroll
        for (int j = 0; j < 4; ++j) s += x4[c][j] * yW1[(4 * c + j) * 10 + r];
      h1t[r] = ftanh(s);
    }
#pragma unroll
    for (int r = 0; r < 10; ++r) {
      float s = yb2[r];
#pragma unroll
      for (int k = 0; k < 10; ++k) s += h1t[k] * yW2[k * 10 + r];
      h2t[r] = ftanh(s);
    }
#pragma unroll
    for (int r = 0; r < 16; ++r) {
      float s = yb3[r];
#pragma unroll
      for (int k = 0; k < 10; ++k) s += h2t[k] * yW3[k * 16 + r];
      y4[r >> 2][r & 3] = s;
    }
  }

  float lcp = 0.0f;
  float dwv = dw[e];   // t=0 increment
  v4f Xn[2], Yn[2];

  // ------------------------------- time loop -------------------------------
#pragma unroll 1
  for (int t = 0; t < kT; ++t) {
    float dwn = (t < kT - 1) ? dw[(t + 1) * kB + e] : 0.0f;
    const float tv = (float)t * kDT;
    const float wt = (t == 0 || t == kT - 1) ? 1.0f : 2.0f;

    // L1 (own MLP, all 10 rows): packed row = [bias, w_t, w_x0..w_x15]
    float hh[10];
#pragma unroll
    for (int r = 0; r < 10; ++r) {
      const float* w = Wl1 + r * 20;
      float s = w[0] + tv * w[1];
#pragma unroll
      for (int c = 0; c < 4; ++c)
#pragma unroll
        for (int j = 0; j < 4; ++j) s += x4[c][j] * w[2 + 4 * c + j];
      hh[r] = ftanh(s);
    }
    // L2 (own MLP, all 10 rows)
    float gg[10];
#pragma unroll
    for (int r = 0; r < 10; ++r) {
      const float* w = Wl2 + r * 12;
      float s = w[0];
#pragma unroll
      for (int k = 0; k < 10; ++k) s += hh[k] * w[1 + k];
      gg[r] = ftanh(s);
    }

    // L3: wave0 -> all 16 Zv rows; wave1 -> all 8 u rows
    v4f zv4[4], u2[2];
    if (q == 0) {
      float z[16];
#pragma unroll
      for (int r = 0; r < 16; ++r) {
        const float* w = Wl3 + r * 12;
        float s = w[0];
#pragma unroll
        for (int k = 0; k < 10; ++k) s += gg[k] * w[1 + k];
        z[r] = s;
      }
#pragma unroll
      for (int c = 0; c < 4; ++c) {
        v4f zz = {z[4 * c], z[4 * c + 1], z[4 * c + 2], z[4 * c + 3]};
        zv4[c] = zz;
        *(v4f*)&ZUt[lane][4 * c] = zz;
      }
    } else {
      float z[8];
#pragma unroll
      for (int r = 0; r < 8; ++r) {
        const float* w = Wl3 + r * 12;
        float s = w[0];
#pragma unroll
        for (int k = 0; k < 10; ++k) s += gg[k] * w[1 + k];
        z[r] = s;
      }
#pragma unroll
      for (int c = 0; c < 2; ++c) {
        v4f zz = {z[4 * c], z[4 * c + 1], z[4 * c + 2], z[4 * c + 3]};
        u2[c] = zz;
        *(v4f*)&ZUt[lane][16 + 4 * c] = zz;
      }
    }
    __syncthreads();                       // B1: ZU visible

    float s2 = 0.0f;
    if (q == 0) {
      u2[0] = *(const v4f*)&ZUt[lane][16];
      u2[1] = *(const v4f*)&ZUt[lane][20];
      asm volatile("" : "+v"(u2[0]), "+v"(u2[1]));
      upd_dh<0>(Wup, Wdh, x4, y4, zv4, u2, dwv, Xn, Yn, s2);
    } else {
#pragma unroll
      for (int c = 0; c < 4; ++c) zv4[c] = *(const v4f*)&ZUt[lane][4 * c];
      asm volatile("" : "+v"(zv4[0]), "+v"(zv4[1]), "+v"(zv4[2]), "+v"(zv4[3]));
      upd_dh<1>(Wup, Wdh, x4, y4, zv4, u2, dwv, Xn, Yn, s2);
    }
    lcp += (0.5f * kDT * kTau * kTau) * wt * s2;

    // Publish own 8 X rows + 8 Y rows (b128 x4)
    *(v4f*)&XYt[lane][8 * q]          = Xn[0];
    *(v4f*)&XYt[lane][8 * q + 4]      = Xn[1];
    *(v4f*)&XYt[lane][16 + 8 * q]     = Yn[0];
    *(v4f*)&XYt[lane][16 + 8 * q + 4] = Yn[1];
    dwv = dwn;
    __syncthreads();                       // B2: XY visible

#pragma unroll
    for (int c = 0; c < 4; ++c) {
      x4[c] = *(const v4f*)&XYt[lane][4 * c];
      y4[c] = *(const v4f*)&XYt[lane][16 + 4 * c];
    }
    asm volatile("" : "+v"(x4[0]), "+v"(x4[1]), "+v"(x4[2]), "+v"(x4[3]),
                      "+v"(y4[0]), "+v"(y4[1]), "+v"(y4[2]), "+v"(y4[3]));
  }

  // ---- losses ----
  float bp = 0.0f;
  if (q == 0) {
#pragma unroll
    for (int c = 0; c < 4; ++c)
#pragma unroll
      for (int j = 0; j < 4; ++j) {
        float d = y4[c][j] - x4[c][j];
        bp += d * d;
      }
  }
#pragma unroll
  for (int s = 32; s > 0; s >>= 1) {
    bp  += __shfl_down(bp,  s, 64);
    lcp += __shfl_down(lcp, s, 64);
  }
  if (lane == 0) {
    if (q == 0) atomicAdd(&out[0], bp * (1.0f / (float)kB));
    atomicAdd(&out[1], lcp * (1.0f / (float)kB));
  }
}

} // namespace

extern "C" void kernel_launch(void* const* d_in, const int* in_sizes, int n_in,
                              void* d_out, int out_size, void* d_ws, size_t ws_size,
                              hipStream_t stream) {
  (void)in_sizes; (void)n_in; (void)ws_size; (void)out_size;

  const float* dw  = (const float*)d_in[0];
  const float* X0  = (const float*)d_in[1];
  const float* A   = (const float*)d_in[2];
  const float* Bm  = (const float*)d_in[3];
  const float* Cm  = (const float*)d_in[4];
  const float* Dm  = (const float*)d_in[5];
  const float* pW1 = (const float*)d_in[6];
  const float* pb1 = (const float*)d_in[7];
  const float* pW2 = (const float*)d_in[8];
  const float* pb2 = (const float*)d_in[9];
  const float* pW3 = (const float*)d_in[10];
  const float* pb3 = (const float*)d_in[11];
  const float* zW1 = (const float*)d_in[12];
  const float* zb1 = (const float*)d_in[13];
  const float* zW2 = (const float*)d_in[14];
  const float* zb2 = (const float*)d_in[15];
  const float* zW3 = (const float*)d_in[16];
  const float* zb3 = (const float*)d_in[17];
  const float* yW1 = (const float*)d_in[18];
  const float* yb1 = (const float*)d_in[19];
  const float* yW2 = (const float*)d_in[20];
  const float* yb2 = (const float*)d_in[21];
  const float* yW3 = (const float*)d_in[22];
  const float* yb3 = (const float*)d_in[23];
  float* out = (float*)d_out;
  float* ws  = (float*)d_ws;

  prep_kernel<<<1, 256, 0, stream>>>(
      A, Bm, Cm, Dm,
      pW1, pb1, pW2, pb2, pW3, pb3,
      zW1, zb1, zW2, zb2, zW3, zb3, ws, out);

  bsde_kernel<<<kB / 64, 128, 0, stream>>>(
      dw, X0, yW1, yb1, yW2, yb2, yW3, yb3, ws, out);
}